// Round 10
// baseline (189.537 us; speedup 1.0000x reference)
//
#include <hip/hip_runtime.h>
#include <hip/hip_cooperative_groups.h>

namespace cg = cooperative_groups;

// BEV pooling (Lift-Splat-Shoot), SINGLE fused cooperative kernel.
//
//   x:    flat (Nprime=473088, C=80) f32
//   geom: flat (Nprime, 3) i32
//   out:  (B, C=80, NZ=16, NX=128, NY=128) f32
//
// Phase A: zero row counters (grid-stride).        grid.sync()
// Phase B: bucket kept points per (b,z,x) row.     grid.sync()
// Phase C: per-row gather (R7 structure): stage bucket -> LDS, 25 slots x
//          20 c-quads float4 x reads, LDS 128x81 acc, REGULAR float4 stores
//          (let L2/L3 absorb the 84MB write stream; no nt).
//
// Rationale: R5-R9 falsified store-width / occupancy / pointer-chase /
// write-contiguity theories (all ~55-60us). This tests the two remaining
// suspects at once: 3-dispatch launch+drain overhead, and nt-store forced
// synchronous HBM writeback.

#define BNX 128
#define BNY 128
#define BNZ 16
#define BC  80
#define ACCP 81                    // padded acc stride (store-phase bank spread)
#define PLANE      (BNX * BNY)     // 16384
#define NSEG_PER_B (BNZ * PLANE)   // 262144
#define ZX         (BNZ * BNX)     // 2048 rows per batch
#define KCAP 256                   // bucket capacity (row mean 27.6, max << 128)
#define GT   512                   // block size
#define GBLK 768                   // target grid (3 blk/CU x 256 CU)

typedef float fvec4 __attribute__((ext_vector_type(4)));

__global__ __launch_bounds__(GT) void lss_fused(
    const float* __restrict__ x,
    const int* __restrict__ geom,
    float* __restrict__ out,
    int* __restrict__ cnt,      // [nrows]
    int* __restrict__ plist,    // [nrows*KCAP]
    int npoints, int per_b, int nrows)
{
    cg::grid_group grid = cg::this_grid();
    const int tid = threadIdx.x;
    const int gsz = (int)(gridDim.x * blockDim.x);
    const int gid = (int)(blockIdx.x * blockDim.x) + tid;

    // ---- phase A: zero counters ----
    for (int i = gid; i < nrows; i += gsz) cnt[i] = 0;
    grid.sync();

    // ---- phase B: bucket points ----
    for (int p = gid; p < npoints; p += gsz) {
        int gx = geom[p * 3 + 0];
        int gy = geom[p * 3 + 1];
        int gz = geom[p * 3 + 2];
        if ((unsigned)gx >= (unsigned)BNX ||
            (unsigned)gy >= (unsigned)BNY ||
            (unsigned)gz >= (unsigned)BNZ) continue;
        int b   = p / per_b;
        int row = b * ZX + gz * BNX + gx;
        int pos = atomicAdd(&cnt[row], 1);
        if (pos < KCAP) plist[(size_t)row * KCAP + pos] = (p << 7) | gy;
    }
    grid.sync();

    // ---- phase C: per-row gather ----
    __shared__ float acc[BNY * ACCP];   // 41.5 KB
    __shared__ int   list[KCAP];        // 1 KB

    const int s  = tid / 20;            // entry slot 0..24 (tid < 500)
    const int cq = tid % 20;            // channel quad
    const int l  = tid & 31;            // store-phase y-quad
    const int c0 = tid >> 5;            // store-phase channel start

    for (int row = blockIdx.x; row < nrows; row += gridDim.x) {
        int n = cnt[row];
        n = n < KCAP ? n : KCAP;

        for (int i = tid; i < n; i += GT) list[i] = plist[(size_t)row * KCAP + i];
        for (int i = tid; i < BNY * ACCP; i += GT) acc[i] = 0.f;
        __syncthreads();

        if (tid < 500) {
            for (int i = s; i < n; i += 25) {
                int e  = list[i];
                int pp = e >> 7;
                int yy = e & 127;
                const fvec4 xv = *reinterpret_cast<const fvec4*>(
                    &x[(size_t)pp * BC + cq * 4]);
                float* a = &acc[yy * ACCP + cq * 4];
                atomicAdd(&a[0], xv.x);
                atomicAdd(&a[1], xv.y);
                atomicAdd(&a[2], xv.z);
                atomicAdd(&a[3], xv.w);
            }
        }
        __syncthreads();

        int b  = row / ZX;
        int zx = row - b * ZX;
        size_t rowbase = (size_t)b * BC * NSEG_PER_B + (size_t)zx * BNY + 4 * l;
        for (int cc = c0; cc < BC; cc += 16) {
            fvec4 v;
            v.x = acc[(4 * l + 0) * ACCP + cc];
            v.y = acc[(4 * l + 1) * ACCP + cc];
            v.z = acc[(4 * l + 2) * ACCP + cc];
            v.w = acc[(4 * l + 3) * ACCP + cc];
            *reinterpret_cast<fvec4*>(&out[rowbase + (size_t)cc * NSEG_PER_B]) = v;
        }
        __syncthreads();   // protect acc/list reuse next row
    }
}

extern "C" void kernel_launch(void* const* d_in, const int* in_sizes, int n_in,
                              void* d_out, int out_size, void* d_ws, size_t ws_size,
                              hipStream_t stream)
{
    const float* x  = (const float*)d_in[0];
    const int* geom = (const int*)d_in[1];
    float* out      = (float*)d_out;

    int npoints = in_sizes[0] / BC;                 // 473088
    int B       = out_size / (BC * NSEG_PER_B);     // 1
    int per_b   = npoints / (B > 0 ? B : 1);
    int nrows   = B * ZX;                           // 2048

    int* cnt   = (int*)d_ws;                        // [nrows]
    int* plist = cnt + nrows;                       // [nrows*KCAP] = 2 MB

    // size cooperative grid to guaranteed co-residency (host queries execute
    // once at capture; they are not stream ops)
    int maxb = 0, ncu = 0, dev = 0;
    hipGetDevice(&dev);
    hipDeviceGetAttribute(&ncu, hipDeviceAttributeMultiprocessorCount, dev);
    hipOccupancyMaxActiveBlocksPerMultiprocessor(&maxb, (const void*)lss_fused, GT, 0);
    int grid = maxb * ncu;
    if (grid > GBLK) grid = GBLK;
    if (grid < 1) grid = 1;

    void* args[] = { (void*)&x, (void*)&geom, (void*)&out,
                     (void*)&cnt, (void*)&plist,
                     (void*)&npoints, (void*)&per_b, (void*)&nrows };
    hipLaunchCooperativeKernel((const void*)lss_fused, dim3(grid), dim3(GT),
                               args, 0, stream);
}

// Round 11
// 105.381 us; speedup vs baseline: 1.7986x; 1.7986x over previous
//
#include <hip/hip_runtime.h>

// BEV pooling (Lift-Splat-Shoot) via CSR-style row buckets, MI355X / gfx950.
// MEASUREMENT ROUND: identical kernels to R7, pipeline launched TWICE in one
// graph (idempotent) to solve dur = OH + k*P for overhead vs kernel time.

#define BNX 128
#define BNY 128
#define BNZ 16
#define BC  80
#define ACCP 81                    // padded acc stride (bank spread for store phase)
#define PLANE      (BNX * BNY)     // 16384
#define NSEG_PER_B (BNZ * PLANE)   // 262144
#define ZX         (BNZ * BNX)     // 2048 rows per batch
#define KCAP 1024                  // bucket capacity (row mean 27.5, sigma ~5)
#define GT 512                     // gather block size

typedef float fvec4 __attribute__((ext_vector_type(4)));

// ---- kernel 0: row_cnt = 0 -------------------------------------------------
__global__ __launch_bounds__(256) void init_cnt(int* __restrict__ cnt, int n)
{
    int i = blockIdx.x * blockDim.x + threadIdx.x;
    if (i < n) cnt[i] = 0;
}

// ---- kernel 1: fill row buckets -------------------------------------------
__global__ __launch_bounds__(256) void fill_buckets(
    const int* __restrict__ geom,
    int* __restrict__ row_cnt,   // [B*ZX]
    int* __restrict__ plist,     // [B*ZX*KCAP], entries (p<<7)|y
    int npoints, int per_b)
{
    int p = blockIdx.x * blockDim.x + threadIdx.x;
    if (p >= npoints) return;

    int gx = geom[p * 3 + 0];
    int gy = geom[p * 3 + 1];
    int gz = geom[p * 3 + 2];
    if ((unsigned)gx >= (unsigned)BNX ||
        (unsigned)gy >= (unsigned)BNY ||
        (unsigned)gz >= (unsigned)BNZ) return;

    int b   = p / per_b;
    int row = b * ZX + gz * BNX + gx;
    int pos = atomicAdd(&row_cnt[row], 1);
    if (pos < KCAP) plist[(size_t)row * KCAP + pos] = (p << 7) | gy;
}

// ---- kernel 2: row gather --------------------------------------------------
__global__ __launch_bounds__(GT) void gather_rows(
    const float* __restrict__ x,
    const int* __restrict__ plist,
    const int* __restrict__ row_cnt,
    float* __restrict__ out)
{
    __shared__ float acc[BNY * ACCP];   // 41.5 KB
    __shared__ int   list[KCAP];        // 4 KB

    const int tid = threadIdx.x;
    const int row = blockIdx.x;                 // b*ZX + zx
    const int b   = row / ZX;
    const int zx  = row - b * ZX;

    int n = row_cnt[row];
    n = n < KCAP ? n : KCAP;

    for (int i = tid; i < n; i += GT) list[i] = plist[(size_t)row * KCAP + i];
    for (int i = tid; i < BNY * ACCP; i += GT) acc[i] = 0.f;
    __syncthreads();

    if (tid < 500) {
        const int s  = tid / 20;      // entry slot 0..24
        const int cq = tid % 20;      // channel quad 0..19
        for (int i = s; i < n; i += 25) {
            int e  = list[i];
            int pp = e >> 7;
            int yy = e & 127;
            const fvec4 xv = *reinterpret_cast<const fvec4*>(
                &x[(size_t)pp * BC + cq * 4]);
            float* a = &acc[yy * ACCP + cq * 4];
            atomicAdd(&a[0], xv.x);
            atomicAdd(&a[1], xv.y);
            atomicAdd(&a[2], xv.z);
            atomicAdd(&a[3], xv.w);
        }
    }
    __syncthreads();

    {
        const int l  = tid & 31;          // y-quad: y = 4l..4l+3
        const int c0 = tid >> 5;          // 0..15
        size_t rowbase = (size_t)b * BC * NSEG_PER_B + (size_t)zx * BNY + 4 * l;
        for (int cc = c0; cc < BC; cc += 16) {
            fvec4 v;
            v.x = acc[(4 * l + 0) * ACCP + cc];
            v.y = acc[(4 * l + 1) * ACCP + cc];
            v.z = acc[(4 * l + 2) * ACCP + cc];
            v.w = acc[(4 * l + 3) * ACCP + cc];
            __builtin_nontemporal_store(v,
                (fvec4*)&out[rowbase + (size_t)cc * NSEG_PER_B]);
        }
    }
}

extern "C" void kernel_launch(void* const* d_in, const int* in_sizes, int n_in,
                              void* d_out, int out_size, void* d_ws, size_t ws_size,
                              hipStream_t stream)
{
    const float* x  = (const float*)d_in[0];
    const int* geom = (const int*)d_in[1];
    float* out      = (float*)d_out;

    const int npoints = in_sizes[0] / BC;                 // 473088
    const int B       = out_size / (BC * NSEG_PER_B);     // 1
    const int per_b   = npoints / (B > 0 ? B : 1);
    const int nrows   = B * ZX;                           // 2048

    int* row_cnt = (int*)d_ws;             // [nrows]
    int* plist   = row_cnt + nrows;        // [nrows*KCAP] = 8 MB

    // pipeline twice (idempotent): dur = OH + 2P, vs R7's OH + P = 56.8us
    for (int rep = 0; rep < 2; ++rep) {
        init_cnt<<<(nrows + 255) / 256, 256, 0, stream>>>(row_cnt, nrows);
        fill_buckets<<<(npoints + 255) / 256, 256, 0, stream>>>(
            geom, row_cnt, plist, npoints, per_b);
        gather_rows<<<nrows, GT, 0, stream>>>(x, plist, row_cnt, out);
    }
}

// Round 12
// 58.747 us; speedup vs baseline: 3.2263x; 1.7938x over previous
//
#include <hip/hip_runtime.h>

// BEV pooling (Lift-Splat-Shoot) via CSR-style row buckets, MI355X / gfx950.
// R12: single-variable A/B vs R8 — nontemporal stores replaced by REGULAR
// cacheable float4 stores (suspect: nt bypasses L2/Infinity-Cache and forces
// synchronous HBM writeback of the 84MB output => ~2.1 TB/s effective cap).

#define BNX 128
#define BNY 128
#define BNZ 16
#define BC  80
#define ACCP 81                    // padded acc stride (bank spread for store phase)
#define PLANE      (BNX * BNY)     // 16384
#define NSEG_PER_B (BNZ * PLANE)   // 262144
#define ZX         (BNZ * BNX)     // 2048 rows per batch
#define KCAP 1024                  // bucket capacity (row mean 27.5, sigma ~5)
#define GT 512                     // gather block size

typedef float fvec4 __attribute__((ext_vector_type(4)));

// ---- kernel 0: row_cnt = 0 -------------------------------------------------
__global__ __launch_bounds__(256) void init_cnt(int* __restrict__ cnt, int n)
{
    int i = blockIdx.x * blockDim.x + threadIdx.x;
    if (i < n) cnt[i] = 0;
}

// ---- kernel 1: fill row buckets -------------------------------------------
__global__ __launch_bounds__(256) void fill_buckets(
    const int* __restrict__ geom,
    int* __restrict__ row_cnt,   // [B*ZX]
    int* __restrict__ plist,     // [B*ZX*KCAP], entries (p<<7)|y
    int npoints, int per_b)
{
    int p = blockIdx.x * blockDim.x + threadIdx.x;
    if (p >= npoints) return;

    int gx = geom[p * 3 + 0];
    int gy = geom[p * 3 + 1];
    int gz = geom[p * 3 + 2];
    if ((unsigned)gx >= (unsigned)BNX ||
        (unsigned)gy >= (unsigned)BNY ||
        (unsigned)gz >= (unsigned)BNZ) return;

    int b   = p / per_b;
    int row = b * ZX + gz * BNX + gx;
    int pos = atomicAdd(&row_cnt[row], 1);
    if (pos < KCAP) plist[(size_t)row * KCAP + pos] = (p << 7) | gy;
}

// ---- kernel 2: row gather --------------------------------------------------
__global__ __launch_bounds__(GT) void gather_rows(
    const float* __restrict__ x,
    const int* __restrict__ plist,
    const int* __restrict__ row_cnt,
    float* __restrict__ out)
{
    __shared__ float acc[BNY * ACCP];   // 41.5 KB
    __shared__ int   list[KCAP];        // 4 KB

    const int tid = threadIdx.x;
    const int row = blockIdx.x;                 // b*ZX + zx
    const int b   = row / ZX;
    const int zx  = row - b * ZX;

    int n = row_cnt[row];
    n = n < KCAP ? n : KCAP;

    for (int i = tid; i < n; i += GT) list[i] = plist[(size_t)row * KCAP + i];
    for (int i = tid; i < BNY * ACCP; i += GT) acc[i] = 0.f;
    __syncthreads();

    if (tid < 500) {
        const int s  = tid / 20;      // entry slot 0..24
        const int cq = tid % 20;      // channel quad 0..19
        for (int i = s; i < n; i += 25) {
            int e  = list[i];
            int pp = e >> 7;
            int yy = e & 127;
            const fvec4 xv = *reinterpret_cast<const fvec4*>(
                &x[(size_t)pp * BC + cq * 4]);
            float* a = &acc[yy * ACCP + cq * 4];
            atomicAdd(&a[0], xv.x);
            atomicAdd(&a[1], xv.y);
            atomicAdd(&a[2], xv.z);
            atomicAdd(&a[3], xv.w);
        }
    }
    __syncthreads();

    // store phase: REGULAR cacheable float4 stores (the one change vs R8)
    {
        const int l  = tid & 31;          // y-quad: y = 4l..4l+3
        const int c0 = tid >> 5;          // 0..15
        size_t rowbase = (size_t)b * BC * NSEG_PER_B + (size_t)zx * BNY + 4 * l;
        for (int cc = c0; cc < BC; cc += 16) {
            fvec4 v;
            v.x = acc[(4 * l + 0) * ACCP + cc];
            v.y = acc[(4 * l + 1) * ACCP + cc];
            v.z = acc[(4 * l + 2) * ACCP + cc];
            v.w = acc[(4 * l + 3) * ACCP + cc];
            *reinterpret_cast<fvec4*>(&out[rowbase + (size_t)cc * NSEG_PER_B]) = v;
        }
    }
}

extern "C" void kernel_launch(void* const* d_in, const int* in_sizes, int n_in,
                              void* d_out, int out_size, void* d_ws, size_t ws_size,
                              hipStream_t stream)
{
    const float* x  = (const float*)d_in[0];
    const int* geom = (const int*)d_in[1];
    float* out      = (float*)d_out;

    const int npoints = in_sizes[0] / BC;                 // 473088
    const int B       = out_size / (BC * NSEG_PER_B);     // 1
    const int per_b   = npoints / (B > 0 ? B : 1);
    const int nrows   = B * ZX;                           // 2048

    int* row_cnt = (int*)d_ws;             // [nrows]
    int* plist   = row_cnt + nrows;        // [nrows*KCAP] = 8 MB

    init_cnt<<<(nrows + 255) / 256, 256, 0, stream>>>(row_cnt, nrows);

    fill_buckets<<<(npoints + 255) / 256, 256, 0, stream>>>(
        geom, row_cnt, plist, npoints, per_b);

    gather_rows<<<nrows, GT, 0, stream>>>(x, plist, row_cnt, out);
}